// Round 7
// baseline (378.678 us; speedup 1.0000x reference)
//
#include <hip/hip_runtime.h>
#include <hip/hip_fp16.h>
#include <math.h>

#define BATCH 2048
#define NFEAT 7
#define CARD 10000
#define CONCAT 256
#define P_HID 512

#define BM 128
#define BN 128
#define BK 64
#define KSPLIT 8              // 512 blocks = exactly 2 per CU (launch_bounds 2)
#define TILES_PER_SPLIT 80    // 640 / 8
#define NUNITS 640            // triangle-packed (i, j-window) units
#define UNIT_ST (512 * 64)    // fp16 elements per unit in blocked St layout
#define PREP_BLOCKS (NUNITS * 2)   // one block per (unit, n-half)

using f16x4   = __attribute__((ext_vector_type(4))) _Float16;
using half8   = __attribute__((ext_vector_type(8))) _Float16;
using floatx4 = __attribute__((ext_vector_type(4))) float;

// async global->LDS DMA, 16 B per lane; LDS dest = wave-uniform base + lane*16
__device__ __forceinline__ void dma16(const _Float16* g, _Float16* l) {
    __builtin_amdgcn_global_load_lds(
        (const __attribute__((address_space(1))) unsigned int*)g,
        (__attribute__((address_space(3))) unsigned int*)l,
        16, 0, 0);
}

// unit u -> (i, jw): pairs (i, j) with j in [jw*64, jw*64+64).
// u<256: diagonal-window units, i=u, jw=i>>6 (entries j<i zeroed in B).
// u>=256: full units, ordered by i with jw > i>>6.
__device__ __forceinline__ void unit_decode(int u, int& i, int& jw) {
    if (u < 256)      { i = u;                jw = u >> 6; }
    else if (u < 448) { int v = u - 256; i = v / 3;        jw = 1 + v % 3; }
    else if (u < 576) { int v = u - 448; i = 64 + (v >> 1); jw = 2 + (v & 1); }
    else              { i = 128 + (u - 576); jw = 3; }
}

// ---------------------------------------------------------------------------
// Kernel 1 (fused pre): unchanged from R4 (was < 99 us, no longer #1).
// ---------------------------------------------------------------------------
__global__ __launch_bounds__(256) void fused_pre(
    const float* __restrict__ dense, const int* __restrict__ sparse,
    const float* __restrict__ emb,
    const float* __restrict__ dw1, const float* __restrict__ db1,
    const float* __restrict__ dw2, const float* __restrict__ db2,
    const float* __restrict__ sw1, const float* __restrict__ sb1,
    const float* __restrict__ sw2, const float* __restrict__ sb2,
    const float* __restrict__ pw1,
    _Float16* __restrict__ cbf, _Float16* __restrict__ St)
{
    __shared__ __align__(16) _Float16 sh[64 * 256];   // 32 KB
    const int tid = threadIdx.x;

    if (blockIdx.x < PREP_BLOCKS) {
        const int u = blockIdx.x >> 1, nh = blockIdx.x & 1;
        const int nb = nh * 256;
        int i, jw;
        unit_decode(u, i, jw);

        // ---- fill: 64 q-rows x 256 n, fp32 sum -> fp16 in LDS ----
#pragma unroll
        for (int m = 0; m < 16; ++m) {
            const int flat = m * 256 + tid;       // [0, 4096)
            const int q = flat >> 6, c4 = flat & 63;
            const int j = (jw << 6) + q;
            floatx4 s = {0.f, 0.f, 0.f, 0.f};
            if (j >= i) {
                s = __builtin_nontemporal_load(
                    (const floatx4*)(pw1 + ((size_t)i * 256 + j) * P_HID + nb + 4 * c4));
                if (j > i) {
                    const floatx4 mv = __builtin_nontemporal_load(
                        (const floatx4*)(pw1 + ((size_t)j * 256 + i) * P_HID + nb + 4 * c4));
                    s += mv;
                }
            }
            f16x4 hv = {(_Float16)s.x, (_Float16)s.y, (_Float16)s.z, (_Float16)s.w};
            *(f16x4*)(sh + q * 256 + 4 * c4) = hv;   // conflict-free
        }
        __syncthreads();

        // ---- transpose + store: thread t owns n-column (nb + t) ----
        const _Float16* col = sh + tid;
        _Float16* outp = St + (size_t)u * UNIT_ST + (size_t)(nb + tid) * 64;
#pragma unroll
        for (int e = 0; e < 8; ++e) {
            half8 o;
#pragma unroll
            for (int r = 0; r < 8; ++r) o[r] = col[(8 * e + r) * 256];
            *(half8*)(outp + 8 * e) = o;
        }
    } else {
        // ---- concat build: 4 batch rows per block, one wave per row ----
        float* smem = (float*)sh;
        const int wv = tid >> 6, t = tid & 63;
        const int b = (blockIdx.x - PREP_BLOCKS) * 4 + wv;
        float* xs   = smem + wv * 13;
        float* bufA = smem + 64  + wv * 64;
        float* bufB = smem + 320 + wv * 64;

        if (t < 13) xs[t] = dense[b * 13 + t];
        __syncthreads();

        float h = db1[t];
#pragma unroll
        for (int d = 0; d < 13; ++d) h += xs[d] * dw1[d * 64 + t];
        bufA[t] = fmaxf(h, 0.f);
        __syncthreads();

        if (t < 32) {
            float o = db2[t];
#pragma unroll
            for (int k = 0; k < 64; ++k) o += bufA[k] * dw2[k * 32 + t];
            cbf[b * 256 + t] = (_Float16)o;
        }

        for (int f = 0; f < NFEAT; ++f) {
            __syncthreads();
            const int idx = sparse[b * NFEAT + f];
            bufB[t] = emb[((size_t)(f * CARD + idx)) * 64 + t];
            __syncthreads();
            float s = sb1[f * 64 + t];
#pragma unroll
            for (int e = 0; e < 64; ++e) s += bufB[e] * sw1[(f * 64 + e) * 64 + t];
            bufA[t] = fmaxf(s, 0.f);
            __syncthreads();
            if (t < 32) {
                float o = sb2[f * 32 + t];
#pragma unroll
                for (int k = 0; k < 64; ++k) o += bufA[k] * sw2[(f * 64 + k) * 32 + t];
                cbf[b * 256 + 32 + f * 32 + t] = (_Float16)o;
            }
        }
    }
}

// ---------------------------------------------------------------------------
// Kernel 2: hidden[b,n] = sum over packed pairs A[b,k] * St[n,k].
// fp16 GEMM M=2048 N=512 K=40960.
// R5: A never touches LDS. Each lane preloads the window chunks for its own
// 4 MFMA rows: per ks-split only 3 distinct jw occur -> pre[4][3][2] half8
// (96 VGPR). Per tile: wave-uniform switch(slot) + pk_mul builds A-fragments
// in registers; ci[4] scalars pipelined one tile ahead (L1-resident cbf).
// B double-buffered in LDS (2x16 KB), ONE __syncthreads per tile; next
// tile's DMA issued before the MFMA phase so the barrier's vmcnt(0) drain
// lands after a full MFMA phase of cover (T3-minimum schedule).
// LDS traffic per block-tile: 96 KB -> 48 KB. launch_bounds(256,2),
// grid 512 = exactly 2 blocks/CU (KSPLIT=8, 80 tiles/split).
// ---------------------------------------------------------------------------
__global__ __launch_bounds__(256, 2) void bilinear_gemm(
    const _Float16* __restrict__ cbf, const _Float16* __restrict__ St,
    _Float16* __restrict__ hidpart)
{
    __shared__ _Float16 Bl[2][BN][BK];    // 2 x 16 KB, XOR-swizzled rows

    // XCD-aware decode: 16 m-blocks of one (nt,ks) slice share one XCD's L2.
    const int b = blockIdx.x;               // 512 blocks, 512%8==0 -> bijective
    const int xcd = b & 7, slot = b >> 3;
    const int mt = slot & 15;
    const int slice = ((slot >> 4) << 3) | xcd;   // 0..31
    const int nt = slice & 3, ks = slice >> 2;    // ks in 0..7
    const int m0 = mt * BM, n0 = nt * BN;
    const int t0 = ks * TILES_PER_SPLIT;

    const int tid = threadIdx.x, lane = tid & 63, wv = tid >> 6;
    const int wrow = (wv & 1) * 64, wcol = (wv >> 1) * 64;
    const int l15 = lane & 15, l4 = lane >> 4, l7 = lane & 7;

    // per-split jw window base: splits use windows {jwbase..jwbase+2} only
    const int jwbase = (0x22111210 >> (ks * 4)) & 0xF;

    floatx4 acc[4][4];
#pragma unroll
    for (int i = 0; i < 4; ++i)
#pragma unroll
        for (int j = 0; j < 4; ++j) acc[i][j] = (floatx4){0.f, 0.f, 0.f, 0.f};

    // A-row base for this lane (rows m0+wrow+i*16+l15, i=0..3 at +i*4096)
    const _Float16* arow_base = cbf + (size_t)(m0 + wrow + l15) * 256;

    // ---- preload window chunks: 4 rows x 3 slots x 2 kh  (96 VGPR) ----
    half8 pre[4][3][2];
#pragma unroll
    for (int i = 0; i < 4; ++i)
#pragma unroll
        for (int s = 0; s < 3; ++s) {
            int jw = jwbase + s; if (jw > 3) jw = 3;   // pad slot, never used
#pragma unroll
            for (int kh = 0; kh < 2; ++kh)
                pre[i][s][kh] = *(const half8*)(arow_base + i * 4096 + (jw << 6)
                                                + kh * 32 + l4 * 8);
        }

    // B staging source (pre-swizzled per-lane global address, blocked St)
    const int drow = wv * 32 + (lane >> 3);
    const int eswz = (lane & 7) ^ ((lane >> 3) & 7);
    const _Float16* bsrc = St + (size_t)t0 * UNIT_ST + (size_t)(n0 + drow) * 64 + eswz * 8;

    // ---- prologue: decode tile 0, load its ci, stage its B ----
    int ui0, ujw0;
    unit_decode(t0, ui0, ujw0);
    int slot_c = ujw0 - jwbase;
    _Float16 ci_c[4];
#pragma unroll
    for (int i = 0; i < 4; ++i) ci_c[i] = arow_base[i * 4096 + ui0];
#pragma unroll
    for (int p = 0; p < 4; ++p)
        dma16(bsrc + (size_t)(p * 8) * 64, &Bl[0][wv * 32 + p * 8][0]);
    bsrc += UNIT_ST;
    __syncthreads();

    int slot_n = 0;
    _Float16 ci_n[4] = {ci_c[0], ci_c[1], ci_c[2], ci_c[3]};

    for (int it = 0; it < TILES_PER_SPLIT; ++it) {
        const int cur = it & 1;

        if (it + 1 < TILES_PER_SPLIT) {
            // issue next tile's B DMA (lands during this tile's MFMA phase)
#pragma unroll
            for (int p = 0; p < 4; ++p)
                dma16(bsrc + (size_t)(p * 8) * 64, &Bl[cur ^ 1][wv * 32 + p * 8][0]);
            bsrc += UNIT_ST;
            // pipeline next tile's ci (completes under the MFMA phase)
            int ui_n, ujw_n;
            unit_decode(t0 + it + 1, ui_n, ujw_n);
            slot_n = ujw_n - jwbase;
#pragma unroll
            for (int i = 0; i < 4; ++i) ci_n[i] = arow_base[i * 4096 + ui_n];
        }

        // ---- MFMA phase on Bl[cur]; A-fragments built in registers ----
        __builtin_amdgcn_s_setprio(1);
#pragma unroll
        for (int kh = 0; kh < 2; ++kh) {
            half8 af[4];
#define ABUILD(S)                                                        \
            {                                                            \
                _Pragma("unroll")                                        \
                for (int i = 0; i < 4; ++i) {                            \
                    const _Float16 c = ci_c[i];                          \
                    const half8 civ = {c, c, c, c, c, c, c, c};          \
                    af[i] = pre[i][S][kh] * civ;                         \
                }                                                        \
            }
            switch (slot_c) {
                case 0:  ABUILD(0); break;
                case 1:  ABUILD(1); break;
                default: ABUILD(2); break;
            }
#undef ABUILD
            const int s = ((kh * 4 + l4) ^ l7) * 8;
            half8 bfr[4];
#pragma unroll
            for (int j = 0; j < 4; ++j)
                bfr[j] = *(const half8*)&Bl[cur][wcol + j * 16 + l15][s];
#pragma unroll
            for (int i = 0; i < 4; ++i)
#pragma unroll
                for (int j = 0; j < 4; ++j)
                    acc[i][j] = __builtin_amdgcn_mfma_f32_16x16x32_f16(
                        af[i], bfr[j], acc[i][j], 0, 0, 0);
        }
        __builtin_amdgcn_s_setprio(0);

        __syncthreads();   // drains this tile's prefetch DMA; swaps buffers
        slot_c = slot_n;
#pragma unroll
        for (int i = 0; i < 4; ++i) ci_c[i] = ci_n[i];
    }

    // epilogue: C/D layout col=lane&15, row=(lane>>4)*4+r (m89-verified)
    _Float16* outp = hidpart + (size_t)ks * BATCH * P_HID;
    const int r0 = m0 + wrow + l4 * 4;
    const int c0 = n0 + wcol + l15;
#pragma unroll
    for (int i = 0; i < 4; ++i)
#pragma unroll
        for (int j = 0; j < 4; ++j)
#pragma unroll
            for (int r = 0; r < 4; ++r)
                outp[(size_t)(r0 + i * 16 + r) * P_HID + c0 + j * 16] =
                    (_Float16)acc[i][j][r];
}

// ---------------------------------------------------------------------------
// Kernel 3: sum k-splits + pb1, ReLU, dot with pw2, +pb2, sigmoid -> f32 out
// Coalesced half8 loads; waves split the 8 k-splits; LDS cross-wave reduce.
// ---------------------------------------------------------------------------
__global__ __launch_bounds__(256) void finalize(
    const _Float16* __restrict__ hidpart,
    const float* __restrict__ pb1,
    const float* __restrict__ pw2,
    const float* __restrict__ pb2,
    float* __restrict__ out)
{
    const int b = blockIdx.x, t = threadIdx.x;
    const int wv = t >> 6, lane = t & 63;

    float acc[8];
#pragma unroll
    for (int k = 0; k < 8; ++k) acc[k] = 0.f;

    // wave wv handles splits {wv, wv+4}; lane owns 8 consec n
#pragma unroll
    for (int si = 0; si < 2; ++si) {
        const int s = wv + 4 * si;
        const half8 v = *(const half8*)(hidpart + (size_t)s * BATCH * P_HID
                                        + (size_t)b * P_HID + lane * 8);
#pragma unroll
        for (int k = 0; k < 8; ++k) acc[k] += (float)v[k];
    }

    __shared__ float red[4 * 512];   // [wave][k*64+lane]
#pragma unroll
    for (int k = 0; k < 8; ++k) red[wv * 512 + k * 64 + lane] = acc[k];
    __syncthreads();

    if (wv == 0) {
        float dot = 0.f;
#pragma unroll
        for (int k = 0; k < 8; ++k) {
            const int n = lane * 8 + k;
            float v = red[k * 64 + lane] + red[512 + k * 64 + lane]
                    + red[1024 + k * 64 + lane] + red[1536 + k * 64 + lane];
            v += pb1[n];
            v = fmaxf(v, 0.f);
            dot += v * pw2[n];
        }
#pragma unroll
        for (int off = 32; off; off >>= 1) dot += __shfl_down(dot, off, 64);
        if (lane == 0) {
            const float s = dot + pb2[0];
            out[b] = 1.f / (1.f + expf(-s));
        }
    }
}

extern "C" void kernel_launch(void* const* d_in, const int* in_sizes, int n_in,
                              void* d_out, int out_size, void* d_ws, size_t ws_size,
                              hipStream_t stream)
{
    const float* dense  = (const float*)d_in[0];
    const int*   sparse = (const int*)d_in[1];
    // d_in[2] tokenizers == arange(CARD): gather index is the sparse value itself
    const float* emb = (const float*)d_in[3];
    const float* dw1 = (const float*)d_in[4];
    const float* db1 = (const float*)d_in[5];
    const float* dw2 = (const float*)d_in[6];
    const float* db2 = (const float*)d_in[7];
    const float* sw1 = (const float*)d_in[8];
    const float* sb1 = (const float*)d_in[9];
    const float* sw2 = (const float*)d_in[10];
    const float* sb2 = (const float*)d_in[11];
    const float* pw1 = (const float*)d_in[12];
    const float* pb1 = (const float*)d_in[13];
    const float* pw2 = (const float*)d_in[14];
    const float* pb2 = (const float*)d_in[15];

    char* ws = (char*)d_ws;
    _Float16* cbf     = (_Float16*)ws;                                   // 1 MB
    _Float16* St      = (_Float16*)(ws + (1 << 20));                     // 40 MB
    _Float16* hidpart = (_Float16*)(ws + (1 << 20) + ((size_t)40 << 20)); // 16 MB (8 splits)

    fused_pre<<<PREP_BLOCKS + BATCH / 4, 256, 0, stream>>>(
        dense, sparse, emb, dw1, db1, dw2, db2, sw1, sb1, sw2, sb2, pw1,
        cbf, St);
    bilinear_gemm<<<16 * 4 * KSPLIT, 256, 0, stream>>>(cbf, St, hidpart);
    finalize<<<BATCH, 256, 0, stream>>>(hidpart, pb1, pw2, pb2, (float*)d_out);
}

// Round 8
// 345.020 us; speedup vs baseline: 1.0976x; 1.0976x over previous
//
#include <hip/hip_runtime.h>
#include <hip/hip_fp16.h>
#include <math.h>

#define BATCH 2048
#define NFEAT 7
#define CARD 10000
#define CONCAT 256
#define P_HID 512

#define BM 128
#define BN 128
#define BK 64
#define KSPLIT 12             // 768 blocks = exactly 3 per CU (launch_bounds 3)
#define NUNITS 640            // triangle-packed (i, j-window) units
#define UNIT_ST (512 * 64)    // fp16 elements per unit in blocked St layout
#define PREP_BLOCKS (NUNITS * 2)   // one block per (unit, n-half)

using f16x4   = __attribute__((ext_vector_type(4))) _Float16;
using half8   = __attribute__((ext_vector_type(8))) _Float16;
using floatx4 = __attribute__((ext_vector_type(4))) float;

// async global->LDS DMA, 16 B per lane; LDS dest = wave-uniform base + lane*16
__device__ __forceinline__ void dma16(const _Float16* g, _Float16* l) {
    __builtin_amdgcn_global_load_lds(
        (const __attribute__((address_space(1))) unsigned int*)g,
        (__attribute__((address_space(3))) unsigned int*)l,
        16, 0, 0);
}

// unit u -> (i, jw): pairs (i, j) with j in [jw*64, jw*64+64).
// u<256: diagonal-window units, i=u, jw=i>>6 (entries j<i zeroed in B).
// u>=256: full units, ordered by i with jw > i>>6.
__device__ __forceinline__ void unit_decode(int u, int& i, int& jw) {
    if (u < 256)      { i = u;                jw = u >> 6; }
    else if (u < 448) { int v = u - 256; i = v / 3;        jw = 1 + v % 3; }
    else if (u < 576) { int v = u - 448; i = 64 + (v >> 1); jw = 2 + (v & 1); }
    else              { i = 128 + (u - 576); jw = 3; }
}

// ks-split ranges over units: 640 = 4*54 + 8*53
__device__ __forceinline__ int split_t0(int ks)     { return ks * 53 + (ks < 4 ? ks : 4); }
__device__ __forceinline__ int split_ntiles(int ks) { return 53 + (ks < 4 ? 1 : 0); }

// ---------------------------------------------------------------------------
// Kernel 1 (fused pre): unchanged (R4 version; < 99 us, not the #1 dispatch).
// ---------------------------------------------------------------------------
__global__ __launch_bounds__(256) void fused_pre(
    const float* __restrict__ dense, const int* __restrict__ sparse,
    const float* __restrict__ emb,
    const float* __restrict__ dw1, const float* __restrict__ db1,
    const float* __restrict__ dw2, const float* __restrict__ db2,
    const float* __restrict__ sw1, const float* __restrict__ sb1,
    const float* __restrict__ sw2, const float* __restrict__ sb2,
    const float* __restrict__ pw1,
    _Float16* __restrict__ cbf, _Float16* __restrict__ St)
{
    __shared__ __align__(16) _Float16 sh[64 * 256];   // 32 KB
    const int tid = threadIdx.x;

    if (blockIdx.x < PREP_BLOCKS) {
        const int u = blockIdx.x >> 1, nh = blockIdx.x & 1;
        const int nb = nh * 256;
        int i, jw;
        unit_decode(u, i, jw);

        // ---- fill: 64 q-rows x 256 n, fp32 sum -> fp16 in LDS ----
#pragma unroll
        for (int m = 0; m < 16; ++m) {
            const int flat = m * 256 + tid;       // [0, 4096)
            const int q = flat >> 6, c4 = flat & 63;
            const int j = (jw << 6) + q;
            floatx4 s = {0.f, 0.f, 0.f, 0.f};
            if (j >= i) {
                s = __builtin_nontemporal_load(
                    (const floatx4*)(pw1 + ((size_t)i * 256 + j) * P_HID + nb + 4 * c4));
                if (j > i) {
                    const floatx4 mv = __builtin_nontemporal_load(
                        (const floatx4*)(pw1 + ((size_t)j * 256 + i) * P_HID + nb + 4 * c4));
                    s += mv;
                }
            }
            f16x4 hv = {(_Float16)s.x, (_Float16)s.y, (_Float16)s.z, (_Float16)s.w};
            *(f16x4*)(sh + q * 256 + 4 * c4) = hv;   // conflict-free
        }
        __syncthreads();

        // ---- transpose + store: thread t owns n-column (nb + t) ----
        const _Float16* col = sh + tid;
        _Float16* outp = St + (size_t)u * UNIT_ST + (size_t)(nb + tid) * 64;
#pragma unroll
        for (int e = 0; e < 8; ++e) {
            half8 o;
#pragma unroll
            for (int r = 0; r < 8; ++r) o[r] = col[(8 * e + r) * 256];
            *(half8*)(outp + 8 * e) = o;
        }
    } else {
        // ---- concat build: 4 batch rows per block, one wave per row ----
        float* smem = (float*)sh;
        const int wv = tid >> 6, t = tid & 63;
        const int b = (blockIdx.x - PREP_BLOCKS) * 4 + wv;
        float* xs   = smem + wv * 13;
        float* bufA = smem + 64  + wv * 64;
        float* bufB = smem + 320 + wv * 64;

        if (t < 13) xs[t] = dense[b * 13 + t];
        __syncthreads();

        float h = db1[t];
#pragma unroll
        for (int d = 0; d < 13; ++d) h += xs[d] * dw1[d * 64 + t];
        bufA[t] = fmaxf(h, 0.f);
        __syncthreads();

        if (t < 32) {
            float o = db2[t];
#pragma unroll
            for (int k = 0; k < 64; ++k) o += bufA[k] * dw2[k * 32 + t];
            cbf[b * 256 + t] = (_Float16)o;
        }

        for (int f = 0; f < NFEAT; ++f) {
            __syncthreads();
            const int idx = sparse[b * NFEAT + f];
            bufB[t] = emb[((size_t)(f * CARD + idx)) * 64 + t];
            __syncthreads();
            float s = sb1[f * 64 + t];
#pragma unroll
            for (int e = 0; e < 64; ++e) s += bufB[e] * sw1[(f * 64 + e) * 64 + t];
            bufA[t] = fmaxf(s, 0.f);
            __syncthreads();
            if (t < 32) {
                float o = sb2[f * 32 + t];
#pragma unroll
                for (int k = 0; k < 64; ++k) o += bufA[k] * sw2[(f * 64 + k) * 32 + t];
                cbf[b * 256 + 32 + f * 32 + t] = (_Float16)o;
            }
        }
    }
}

// ---------------------------------------------------------------------------
// Kernel 2: hidden[b,n] = sum over packed pairs A[b,k] * St[n,k].
// fp16 GEMM M=2048 N=512 K=40960.
// R7: R4's proven skeleton (LDS A-gen from hoisted pre[4][4] windows; 64 VGPR
// for pre + 64 acc AGPR -> 3 blocks/CU) with the two counter-indicted costs
// removed:
//  * B DOUBLE-BUFFERED + COUNTED vmcnt: dma(it+1) issued at top; barrier1
//    waits vmcnt(5) (4 dma + 1 pipelined ci outstanding) not 0 -> tile-it's
//    DMA covered by a full iteration (A-gen + MFMA), never drained mid-loop.
//  * A packed [128][64] + XOR swizzle (byte ^= (row&7)<<4): conflict-free
//    b128 writes (2 thr/row) AND reads (16-lane column) vs R4's 5.24M
//    conflicts on the padded [128][72] layout. LDS 48 KB/block, 3/CU=144 KB.
// R5 lesson applied: occupancy (3 blocks/CU) beats removing A's LDS trip.
// ---------------------------------------------------------------------------
__global__ __launch_bounds__(256, 3) void bilinear_gemm(
    const _Float16* __restrict__ cbf, const _Float16* __restrict__ St,
    _Float16* __restrict__ hidpart)
{
    __shared__ __align__(16) _Float16 Al[BM * BK];   // 16 KB packed, XOR-swizzled
    __shared__ _Float16 Bl[2][BN][BK];               // 2 x 16 KB, XOR-swizzled

    // XCD-aware decode: 16 m-blocks of one (nt,ks) slice share one XCD's L2.
    const int b = blockIdx.x;               // 768 blocks, 768%8==0 -> bijective
    const int xcd = b & 7, slot = b >> 3;
    const int mt = slot & 15;
    const int slice = ((slot >> 4) << 3) | xcd;   // 0..47
    const int nt = slice & 3, ks = slice >> 2;    // ks in 0..11
    const int m0 = mt * BM, n0 = nt * BN;
    const int t0 = split_t0(ks);
    const int ntiles = split_ntiles(ks);

    const int tid = threadIdx.x, lane = tid & 63, wv = tid >> 6;
    const int wrow = (wv & 1) * 64, wcol = (wv >> 1) * 64;
    const int l15 = lane & 15, l4 = lane >> 4, l7 = lane & 7;
    const int arow = tid >> 1, ajoff = (tid & 1) * 32;  // A-gen: 2 thr/row

    floatx4 acc[4][4];
#pragma unroll
    for (int i = 0; i < 4; ++i)
#pragma unroll
        for (int j = 0; j < 4; ++j) acc[i][j] = (floatx4){0.f, 0.f, 0.f, 0.f};

    const _Float16* crow = cbf + (m0 + arow) * 256;

    // ---- hoisted window preload: all 4 possible jw windows (64 VGPR) ----
    half8 pre[4][4];
#pragma unroll
    for (int jw = 0; jw < 4; ++jw)
#pragma unroll
        for (int x = 0; x < 4; ++x)
            pre[jw][x] = *(const half8*)(crow + (jw << 6) + ajoff + 8 * x);

    // A-gen write base (XOR-swizzled packed rows, 128 B each)
    char* awbase = (char*)Al + arow * 128;
    const int awsz = (arow & 7) << 4;

    // B staging source (pre-swizzled per-lane global address, blocked St)
    const int drow = wv * 32 + (lane >> 3);
    const int eswz = (lane & 7) ^ ((lane >> 3) & 7);
    const _Float16* bsrc = St + (size_t)t0 * UNIT_ST + (size_t)(n0 + drow) * 64 + eswz * 8;

    // ---- prologue: tile-0 decode + ci, stage tile 0 into Bl[0] ----
    int ui_c, ujw_c;
    unit_decode(t0, ui_c, ujw_c);
    _Float16 ci_c = crow[ui_c];
#pragma unroll
    for (int p = 0; p < 4; ++p)
        dma16(bsrc + (size_t)(p * 8) * 64, &Bl[0][wv * 32 + p * 8][0]);
    bsrc += UNIT_ST;

    for (int it = 0; it < ntiles; ++it) {
        const int cur = it & 1;
        const bool more = (it + 1 < ntiles);

        // ---- issue next tile's B DMA into the other buffer ----
        if (more) {
#pragma unroll
            for (int p = 0; p < 4; ++p)
                dma16(bsrc + (size_t)(p * 8) * 64, &Bl[cur ^ 1][wv * 32 + p * 8][0]);
            bsrc += UNIT_ST;
        }

        // ---- A-gen(it): pre[ujw] * ci -> swizzled LDS (covers DMA issue) ----
        {
            const half8 civ = {ci_c, ci_c, ci_c, ci_c, ci_c, ci_c, ci_c, ci_c};
#define AGEN(JW)                                                              \
            { *(half8*)(awbase + ((ajoff * 2 +  0) ^ awsz)) = pre[JW][0] * civ; \
              *(half8*)(awbase + ((ajoff * 2 + 16) ^ awsz)) = pre[JW][1] * civ; \
              *(half8*)(awbase + ((ajoff * 2 + 32) ^ awsz)) = pre[JW][2] * civ; \
              *(half8*)(awbase + ((ajoff * 2 + 48) ^ awsz)) = pre[JW][3] * civ; }
            switch (ujw_c) {
                case 0:  AGEN(0); break;
                case 1:  AGEN(1); break;
                case 2:  AGEN(2); break;
                default: AGEN(3); break;
            }
#undef AGEN
        }

        // ---- pipeline next tile's ci scalar (1 vmem op, L1-resident) ----
        if (more) {
            int ui_n, ujw_n;
            unit_decode(t0 + it + 1, ui_n, ujw_n);
            ujw_c = ujw_n;            // A-gen(it) already consumed old value
            ci_c = crow[ui_n];
        }

        // ---- barrier1: counted vmcnt (never 0 mid-loop) + lgkm drain ----
        if (more) asm volatile("s_waitcnt vmcnt(5) lgkmcnt(0)" ::: "memory");
        else      asm volatile("s_waitcnt vmcnt(0) lgkmcnt(0)" ::: "memory");
        __builtin_amdgcn_s_barrier();
        __builtin_amdgcn_sched_barrier(0);

        // ---- MFMA: 2 k-steps of 32, 4x4 16x16 tiles per wave ----
        __builtin_amdgcn_s_setprio(1);
#pragma unroll
        for (int kh = 0; kh < 2; ++kh) {
            half8 af[4], bfr[4];
#pragma unroll
            for (int i = 0; i < 4; ++i) {
                const int r = wrow + i * 16 + l15;
                const int cb = (kh * 64 + l4 * 16) ^ ((r & 7) << 4);
                af[i] = *(const half8*)((const char*)Al + r * 128 + cb);
            }
            const int s = ((kh * 4 + l4) ^ l7) * 8;
#pragma unroll
            for (int j = 0; j < 4; ++j)
                bfr[j] = *(const half8*)&Bl[cur][wcol + j * 16 + l15][s];
#pragma unroll
            for (int i = 0; i < 4; ++i)
#pragma unroll
                for (int j = 0; j < 4; ++j)
                    acc[i][j] = __builtin_amdgcn_mfma_f32_16x16x32_f16(
                        af[i], bfr[j], acc[i][j], 0, 0, 0);
        }
        __builtin_amdgcn_s_setprio(0);

        // ---- barrier2: A/B reuse guard (no vmcnt drain needed) ----
        __builtin_amdgcn_sched_barrier(0);
        __builtin_amdgcn_s_barrier();
    }

    // epilogue: C/D layout col=lane&15, row=(lane>>4)*4+r (m89-verified)
    _Float16* outp = hidpart + (size_t)ks * BATCH * P_HID;
    const int r0 = m0 + wrow + l4 * 4;
    const int c0 = n0 + wcol + l15;
#pragma unroll
    for (int i = 0; i < 4; ++i)
#pragma unroll
        for (int j = 0; j < 4; ++j)
#pragma unroll
            for (int r = 0; r < 4; ++r)
                outp[(size_t)(r0 + i * 16 + r) * P_HID + c0 + j * 16] =
                    (_Float16)acc[i][j][r];
}

// ---------------------------------------------------------------------------
// Kernel 3: sum k-splits + pb1, ReLU, dot with pw2, +pb2, sigmoid -> f32 out
// Coalesced half8 loads; waves split the 12 k-splits; LDS cross-wave reduce.
// ---------------------------------------------------------------------------
__global__ __launch_bounds__(256) void finalize(
    const _Float16* __restrict__ hidpart,
    const float* __restrict__ pb1,
    const float* __restrict__ pw2,
    const float* __restrict__ pb2,
    float* __restrict__ out)
{
    const int b = blockIdx.x, t = threadIdx.x;
    const int wv = t >> 6, lane = t & 63;

    float acc[8];
#pragma unroll
    for (int k = 0; k < 8; ++k) acc[k] = 0.f;

    // wave wv handles splits {wv, wv+4, wv+8}; lane owns 8 consec n
#pragma unroll
    for (int si = 0; si < 3; ++si) {
        const int s = wv + 4 * si;
        const half8 v = *(const half8*)(hidpart + (size_t)s * BATCH * P_HID
                                        + (size_t)b * P_HID + lane * 8);
#pragma unroll
        for (int k = 0; k < 8; ++k) acc[k] += (float)v[k];
    }

    __shared__ float red[4 * 512];   // [wave][k*64+lane]
#pragma unroll
    for (int k = 0; k < 8; ++k) red[wv * 512 + k * 64 + lane] = acc[k];
    __syncthreads();

    if (wv == 0) {
        float dot = 0.f;
#pragma unroll
        for (int k = 0; k < 8; ++k) {
            const int n = lane * 8 + k;
            float v = red[k * 64 + lane] + red[512 + k * 64 + lane]
                    + red[1024 + k * 64 + lane] + red[1536 + k * 64 + lane];
            v += pb1[n];
            v = fmaxf(v, 0.f);
            dot += v * pw2[n];
        }
#pragma unroll
        for (int off = 32; off; off >>= 1) dot += __shfl_down(dot, off, 64);
        if (lane == 0) {
            const float s = dot + pb2[0];
            out[b] = 1.f / (1.f + expf(-s));
        }
    }
}

extern "C" void kernel_launch(void* const* d_in, const int* in_sizes, int n_in,
                              void* d_out, int out_size, void* d_ws, size_t ws_size,
                              hipStream_t stream)
{
    const float* dense  = (const float*)d_in[0];
    const int*   sparse = (const int*)d_in[1];
    // d_in[2] tokenizers == arange(CARD): gather index is the sparse value itself
    const float* emb = (const float*)d_in[3];
    const float* dw1 = (const float*)d_in[4];
    const float* db1 = (const float*)d_in[5];
    const float* dw2 = (const float*)d_in[6];
    const float* db2 = (const float*)d_in[7];
    const float* sw1 = (const float*)d_in[8];
    const float* sb1 = (const float*)d_in[9];
    const float* sw2 = (const float*)d_in[10];
    const float* sb2 = (const float*)d_in[11];
    const float* pw1 = (const float*)d_in[12];
    const float* pb1 = (const float*)d_in[13];
    const float* pw2 = (const float*)d_in[14];
    const float* pb2 = (const float*)d_in[15];

    char* ws = (char*)d_ws;
    _Float16* cbf     = (_Float16*)ws;                                   // 1 MB
    _Float16* St      = (_Float16*)(ws + (1 << 20));                     // 40 MB
    _Float16* hidpart = (_Float16*)(ws + (1 << 20) + ((size_t)40 << 20)); // 24 MB (12 splits)

    fused_pre<<<PREP_BLOCKS + BATCH / 4, 256, 0, stream>>>(
        dense, sparse, emb, dw1, db1, dw2, db2, sw1, sb1, sw2, sb2, pw1,
        cbf, St);
    bilinear_gemm<<<16 * 4 * KSPLIT, 256, 0, stream>>>(cbf, St, hidpart);
    finalize<<<BATCH, 256, 0, stream>>>(hidpart, pb1, pw2, pb2, (float*)d_out);
}